// Round 2
// baseline (7779.843 us; speedup 1.0000x reference)
//
#include <hip/hip_runtime.h>
#include <stdint.h>

// Problem: B=8, C=192, HEADS=8, hd=24, H=W=128, hw=16384.
// I/O tensors fp32 (per reference); big intermediates bf16; fp32 accumulation.

#define HW 16384
#define WIDTH 128

__device__ __forceinline__ float b2f(uint16_t u) {
    union { uint32_t i; float f; } v; v.i = (uint32_t)u << 16; return v.f;
}
__device__ __forceinline__ uint16_t f2b(float f) {
    union { float f; uint32_t i; } v; v.f = f;
    uint32_t r = v.i + 0x7FFFu + ((v.i >> 16) & 1u);
    return (uint16_t)(r >> 16);
}
// generic load (fp32 or bf16 source) and store
__device__ __forceinline__ float ldv(const float* p) { return *p; }
__device__ __forceinline__ float ldv(const uint16_t* p) { return b2f(*p); }
__device__ __forceinline__ void stv(float* p, float v) { *p = v; }
__device__ __forceinline__ void stv(uint16_t* p, float v) { *p = f2b(v); }

// ---------------------------------------------------------------------------
// prep: transpose 1x1 weights to [ci][co]; copy dw weights + temperature
// ---------------------------------------------------------------------------
__global__ __launch_bounds__(256) void prep(
    const float* __restrict__ kvw,   // [384][192]
    const float* __restrict__ pjw,   // [192][192]
    const float* __restrict__ dww,   // [384][9]
    const float* __restrict__ temp,  // [8]
    float* __restrict__ kvwT,        // [192][384]
    float* __restrict__ pjwT,        // [192][192]
    float* __restrict__ dw32,        // [384][9]
    float* __restrict__ t32)         // [8]
{
    int i = blockIdx.x * 256 + threadIdx.x;
    if (i < 384 * 192) { int co = i / 192, ci = i % 192; kvwT[ci * 384 + co] = kvw[i]; }
    if (i < 192 * 192) { int co = i / 192, ci = i % 192; pjwT[ci * 192 + co] = pjw[i]; }
    if (i < 384 * 9)   dw32[i] = dww[i];
    if (i < 8)         t32[i] = temp[i];
}

// ---------------------------------------------------------------------------
// fold_qw: W'[ci][t][co] = sum_cm qdw[co][cm][t] * qw[cm][ci]   (fp32)
// ---------------------------------------------------------------------------
__global__ __launch_bounds__(256) void fold_qw(
    const float* __restrict__ qw,   // [192 cm][192 ci]
    const float* __restrict__ qdw,  // [192 co][192 cm][9 t]
    float* __restrict__ WP)         // [192 ci][9 t][192 co]
{
    int ci = blockIdx.x, t = blockIdx.y;
    int co = threadIdx.x;  // blockDim = 192
    float s = 0.f;
    for (int cm = 0; cm < 192; cm++)
        s = fmaf(qdw[((size_t)co * 192 + cm) * 9 + t], qw[cm * 192 + ci], s);
    WP[((size_t)ci * 9 + t) * 192 + co] = s;
}

// ---------------------------------------------------------------------------
// conv1x1: O[b][co][p] = sum_ci WT[ci][co] * X[b][ci][p]
// block = 256 thr = 128 px x 2 co-groups; x-tile (192x128 bf16 = 48 KB) in LDS
// ---------------------------------------------------------------------------
template <int COUT, typename TIN, typename TOUT>
__global__ __launch_bounds__(256) void conv1x1(
    const TIN* __restrict__ X, const float* __restrict__ WT,
    TOUT* __restrict__ O)
{
    __shared__ uint16_t xt[192 * 128];
    const int b = blockIdx.y;
    const int p0 = blockIdx.x * 128;
    const TIN* xb = X + ((size_t)b * 192) * HW + p0;
    for (int i = threadIdx.x; i < 192 * 128; i += 256)
        xt[i] = f2b(ldv(&xb[((size_t)(i >> 7)) * HW + (i & 127)]));
    __syncthreads();
    const int px  = threadIdx.x & 127;
    const int cog = threadIdx.x >> 7;  // 0 or 1
    const int coBeg = cog * (COUT / 2);
    TOUT* ob = O + ((size_t)b * COUT) * HW + p0 + px;
    for (int co0 = coBeg; co0 < coBeg + COUT / 2; co0 += 16) {
        float acc[16];
#pragma unroll
        for (int j = 0; j < 16; j++) acc[j] = 0.f;
        for (int ci = 0; ci < 192; ci++) {
            float xv = b2f(xt[(ci << 7) + px]);
            const float* w = WT + ci * COUT + co0;
#pragma unroll
            for (int j = 0; j < 16; j++) acc[j] = fmaf(w[j], xv, acc[j]);
        }
#pragma unroll
        for (int j = 0; j < 16; j++) stv(&ob[((size_t)(co0 + j)) * HW], acc[j]);
    }
}

// ---------------------------------------------------------------------------
// dwconv: depthwise 3x3, SAME zero pad. One thread per output pixel.
// ---------------------------------------------------------------------------
__global__ __launch_bounds__(256) void dwconv(
    const uint16_t* __restrict__ KV1, const float* __restrict__ DW,
    uint16_t* __restrict__ KVo)
{
    const int c = blockIdx.y, b = blockIdx.z;
    const int p = blockIdx.x * 256 + threadIdx.x;
    const int yy = p >> 7, xx = p & 127;
    const uint16_t* src = KV1 + ((size_t)b * 384 + c) * HW;
    const float* w = DW + c * 9;
    float acc = 0.f;
#pragma unroll
    for (int ky = 0; ky < 3; ky++) {
        const int ny = yy + ky - 1;
#pragma unroll
        for (int kx = 0; kx < 3; kx++) {
            const int nx = xx + kx - 1;
            float v = ((unsigned)ny < 128u && (unsigned)nx < 128u)
                          ? b2f(src[ny * WIDTH + nx]) : 0.f;
            acc = fmaf(w[ky * 3 + kx], v, acc);
        }
    }
    KVo[((size_t)b * 384 + c) * HW + p] = f2b(acc);
}

// ---------------------------------------------------------------------------
// conv3x3: dense 3x3 with folded weight W'[ci][t][co].
// Tile 32x8 px per block (256 thr, 1 px/thr), ci staged in 4 chunks of 48
// (LDS 48 x 10 x 34 bf16 = 32640 B), co register-blocked by 16.
// ---------------------------------------------------------------------------
__global__ __launch_bounds__(256) void conv3x3(
    const float* __restrict__ Y, const float* __restrict__ WP,
    uint16_t* __restrict__ Q)
{
    __shared__ uint16_t yt[48 * 340];  // [ci][dy(10)][dx(34)]
    const int b = blockIdx.z;
    const int y0 = blockIdx.y * 8, x0 = blockIdx.x * 32;
    const int tx = threadIdx.x & 31, ty = threadIdx.x >> 5;
    const float* yb = Y + ((size_t)b * 192) * HW;
    uint16_t* qb = Q + ((size_t)b * 192) * HW + (y0 + ty) * WIDTH + (x0 + tx);
    for (int co0 = 0; co0 < 192; co0 += 16) {
        float acc[16];
#pragma unroll
        for (int j = 0; j < 16; j++) acc[j] = 0.f;
        for (int cc = 0; cc < 4; cc++) {
            __syncthreads();
            for (int i = threadIdx.x; i < 48 * 340; i += 256) {
                int ci = i / 340, r = i - ci * 340;
                int dy = r / 34, dx = r - dy * 34;
                int gy = y0 + dy - 1, gx = x0 + dx - 1;
                uint16_t v = 0;
                if ((unsigned)gy < 128u && (unsigned)gx < 128u)
                    v = f2b(yb[((size_t)(cc * 48 + ci)) * HW + gy * WIDTH + gx]);
                yt[i] = v;
            }
            __syncthreads();
            for (int ci = 0; ci < 48; ci++) {
                const uint16_t* bse = &yt[ci * 340 + ty * 34 + tx];
                float yv[9];
#pragma unroll
                for (int ky = 0; ky < 3; ky++)
#pragma unroll
                    for (int kx = 0; kx < 3; kx++)
                        yv[ky * 3 + kx] = b2f(bse[ky * 34 + kx]);
                const float* w = WP + ((size_t)(cc * 48 + ci) * 9) * 192 + co0;
#pragma unroll
                for (int t = 0; t < 9; t++)
#pragma unroll
                    for (int j = 0; j < 16; j++)
                        acc[j] = fmaf(w[t * 192 + j], yv[t], acc[j]);
            }
        }
#pragma unroll
        for (int j = 0; j < 16; j++) qb[((size_t)(co0 + j)) * HW] = f2b(acc[j]);
    }
}

// ---------------------------------------------------------------------------
// rownorm: 1/max(||row||,eps) for q rows (which=0) and k rows (which=1)
// ---------------------------------------------------------------------------
__global__ __launch_bounds__(256) void rownorm(
    const uint16_t* __restrict__ Q, const uint16_t* __restrict__ KV,
    float* __restrict__ invq, float* __restrict__ invk)
{
    int idx = blockIdx.x;                 // [b(8)][which(2)][hc(192)]
    int b = idx / 384, rem = idx % 384;
    int which = rem / 192, hc = rem % 192;
    const uint16_t* src = which ? (KV + ((size_t)b * 384 + hc) * HW)
                                : (Q  + ((size_t)b * 192 + hc) * HW);
    float s = 0.f;
    for (int e = threadIdx.x; e < HW; e += 256) {
        float v = b2f(src[e]); s = fmaf(v, v, s);
    }
#pragma unroll
    for (int o = 32; o > 0; o >>= 1) s += __shfl_down(s, o);
    __shared__ float red[4];
    if ((threadIdx.x & 63) == 0) red[threadIdx.x >> 6] = s;
    __syncthreads();
    if (threadIdx.x == 0) {
        float t = red[0] + red[1] + red[2] + red[3];
        (which ? invk : invq)[b * 192 + hc] = 1.f / fmaxf(sqrtf(t), 1e-12f);
    }
}

// ---------------------------------------------------------------------------
// attn_dots: partial (over e-range) raw dot products q_c . k_d
// grid (8 splits, 64 bh); LDS-staged 24x512 tiles of q and k
// ---------------------------------------------------------------------------
__global__ __launch_bounds__(256) void attn_dots(
    const uint16_t* __restrict__ Q, const uint16_t* __restrict__ KV,
    float* __restrict__ part)   // [8 s][64 bh][576]
{
    const int s = blockIdx.x, bh = blockIdx.y;
    const int b = bh >> 3, h = bh & 7;
    __shared__ uint16_t qt[24 * 512];
    __shared__ uint16_t kt[24 * 512];
    const uint16_t* qb = Q  + ((size_t)b * 192 + h * 24) * HW;
    const uint16_t* kb = KV + ((size_t)b * 384 + h * 24) * HW;
    float accs[3] = {0.f, 0.f, 0.f};
    for (int st = 0; st < 4; st++) {
        const int e0 = s * 2048 + st * 512;
        __syncthreads();
        for (int i = threadIdx.x; i < 24 * 512; i += 256) {
            int c = i >> 9, e = i & 511;
            qt[i] = qb[(size_t)c * HW + e0 + e];
            kt[i] = kb[(size_t)c * HW + e0 + e];
        }
        __syncthreads();
        int ai = 0;
        for (int pi = threadIdx.x; pi < 576; pi += 256, ai++) {
            int c = pi / 24, d = pi - c * 24;
            const uint16_t* qr = &qt[c << 9];
            const uint16_t* kr = &kt[d << 9];
            float a = 0.f;
            for (int e = 0; e < 512; e++) a = fmaf(b2f(qr[e]), b2f(kr[e]), a);
            accs[ai] += a;
        }
    }
    int ai = 0;
    for (int pi = threadIdx.x; pi < 576; pi += 256, ai++)
        part[((size_t)s * 64 + bh) * 576 + pi] = accs[ai];
}

// ---------------------------------------------------------------------------
// softmax_attn: sum partials, scale by temp*invq*invk, row softmax (24x24)
// ---------------------------------------------------------------------------
__global__ __launch_bounds__(256) void softmax_attn(
    const float* __restrict__ part, const float* __restrict__ t32,
    const float* __restrict__ invq, const float* __restrict__ invk,
    float* __restrict__ prob)   // [64 bh][576]
{
    const int bh = blockIdx.x, b = bh >> 3, h = bh & 7;
    __shared__ float l[576];
    const float t = t32[h];
    for (int pi = threadIdx.x; pi < 576; pi += 256) {
        float ssum = 0.f;
        for (int s = 0; s < 8; s++) ssum += part[((size_t)s * 64 + bh) * 576 + pi];
        int c = pi / 24, d = pi - c * 24;
        l[pi] = t * invq[b * 192 + h * 24 + c] * invk[b * 192 + h * 24 + d] * ssum;
    }
    __syncthreads();
    if (threadIdx.x < 24) {
        const int c = threadIdx.x;
        float m = -1e30f;
#pragma unroll
        for (int d = 0; d < 24; d++) m = fmaxf(m, l[c * 24 + d]);
        float ex[24]; float sum = 0.f;
#pragma unroll
        for (int d = 0; d < 24; d++) { ex[d] = __expf(l[c * 24 + d] - m); sum += ex[d]; }
        const float inv = 1.f / sum;
#pragma unroll
        for (int d = 0; d < 24; d++) prob[(size_t)bh * 576 + c * 24 + d] = ex[d] * inv;
    }
}

// ---------------------------------------------------------------------------
// attn_v: AO[b][h*24+c][e] = sum_d prob[c][d] * v[d][e]
// ---------------------------------------------------------------------------
__global__ __launch_bounds__(256) void attn_v(
    const float* __restrict__ prob, const uint16_t* __restrict__ KV,
    uint16_t* __restrict__ AO)
{
    const int bh = blockIdx.y, b = bh >> 3, h = bh & 7;
    const int e = blockIdx.x * 256 + threadIdx.x;
    __shared__ float a[576];
    for (int i = threadIdx.x; i < 576; i += 256) a[i] = prob[(size_t)bh * 576 + i];
    __syncthreads();
    const uint16_t* vb = KV + ((size_t)b * 384 + 192 + h * 24) * HW + e;
    float acc[24];
#pragma unroll
    for (int c = 0; c < 24; c++) acc[c] = 0.f;
    for (int d = 0; d < 24; d++) {
        float vv = b2f(vb[(size_t)d * HW]);
#pragma unroll
        for (int c = 0; c < 24; c++) acc[c] = fmaf(a[c * 24 + d], vv, acc[c]);
    }
    uint16_t* ob = AO + ((size_t)b * 192 + h * 24) * HW + e;
#pragma unroll
    for (int c = 0; c < 24; c++) ob[(size_t)c * HW] = f2b(acc[c]);
}

// ---------------------------------------------------------------------------
extern "C" void kernel_launch(void* const* d_in, const int* in_sizes, int n_in,
                              void* d_out, int out_size, void* d_ws, size_t ws_size,
                              hipStream_t stream) {
    const float* x    = (const float*)d_in[0];
    const float* y    = (const float*)d_in[1];
    const float* temp = (const float*)d_in[2];
    const float* kvw  = (const float*)d_in[3];
    const float* kvdw = (const float*)d_in[4];
    const float* qw   = (const float*)d_in[5];
    const float* qdw  = (const float*)d_in[6];
    const float* pjw  = (const float*)d_in[7];

    char* ws = (char*)d_ws;
    // region reuse: kv1 [0,100.7MB) is dead after dwconv; q and attn-out recycle it
    uint16_t* kv1 = (uint16_t*)(ws + 0);            // 8*384*16384*2 = 100663296
    uint16_t* q   = (uint16_t*)(ws + 0);            // 50331648 (after kv1 dead)
    uint16_t* ao  = (uint16_t*)(ws + 50331648);     // 50331648
    uint16_t* kv  = (uint16_t*)(ws + 100663296);    // 100663296
    float* WP     = (float*)(ws + 201326592);       // 192*9*192*4 = 1327104
    float* kvwT   = (float*)(ws + 202653696);       // 294912
    float* pjwT   = (float*)(ws + 202948608);       // 147456
    float* dw32   = (float*)(ws + 203096064);       // 13824
    float* t32    = (float*)(ws + 203109888);       // 32
    float* invq   = (float*)(ws + 203109920);       // 6144
    float* invk   = (float*)(ws + 203116064);       // 6144
    float* part   = (float*)(ws + 203122208);       // 8*64*576*4 = 1179648
    float* prob   = (float*)(ws + 204301856);       // 147456  -> total ~204.4 MB

    prep<<<288, 256, 0, stream>>>(kvw, pjw, kvdw, temp, kvwT, pjwT, dw32, t32);
    fold_qw<<<dim3(192, 9), 192, 0, stream>>>(qw, qdw, WP);
    conv1x1<384, float, uint16_t><<<dim3(128, 8), 256, 0, stream>>>(x, kvwT, kv1);
    dwconv<<<dim3(64, 384, 8), 256, 0, stream>>>(kv1, dw32, kv);
    conv3x3<<<dim3(4, 16, 8), 256, 0, stream>>>(y, WP, q);
    rownorm<<<3072, 256, 0, stream>>>(q, kv, invq, invk);
    attn_dots<<<dim3(8, 64), 256, 0, stream>>>(q, kv, part);
    softmax_attn<<<64, 256, 0, stream>>>(part, t32, invq, invk, prob);
    attn_v<<<dim3(64, 64), 256, 0, stream>>>(prob, kv, ao);
    conv1x1<192, uint16_t, float><<<dim3(128, 8), 256, 0, stream>>>(ao, pjwT, (float*)d_out);
}

// Round 3
// 2497.177 us; speedup vs baseline: 3.1155x; 3.1155x over previous
//
#include <hip/hip_runtime.h>
#include <stdint.h>

// Problem: B=8, C=192, HEADS=8, hd=24, H=W=128, hw=16384.
// I/O tensors fp32 (per reference); big intermediates bf16; fp32 accumulation.
// conv3x3 (q path) = MFMA implicit GEMM over channel-last Yc + folded W (bf16).

#define HW 16384
#define WIDTH 128

typedef __attribute__((ext_vector_type(8))) short short8;   // 8 bf16 = 4 VGPRs
typedef __attribute__((ext_vector_type(4))) float f32x4;
typedef __attribute__((ext_vector_type(4))) unsigned int u32x4;

__device__ __forceinline__ float b2f(uint16_t u) {
    union { uint32_t i; float f; } v; v.i = (uint32_t)u << 16; return v.f;
}
__device__ __forceinline__ uint16_t f2b(float f) {
    union { float f; uint32_t i; } v; v.f = f;
    uint32_t r = v.i + 0x7FFFu + ((v.i >> 16) & 1u);
    return (uint16_t)(r >> 16);
}
__device__ __forceinline__ float ldv(const float* p) { return *p; }
__device__ __forceinline__ float ldv(const uint16_t* p) { return b2f(*p); }
__device__ __forceinline__ void stv(float* p, float v) { *p = v; }
__device__ __forceinline__ void stv(uint16_t* p, float v) { *p = f2b(v); }

// ---------------------------------------------------------------------------
// prep: transpose 1x1 weights to [ci][co]; copy dw weights + temperature
// ---------------------------------------------------------------------------
__global__ __launch_bounds__(256) void prep(
    const float* __restrict__ kvw,   // [384][192]
    const float* __restrict__ pjw,   // [192][192]
    const float* __restrict__ dww,   // [384][9]
    const float* __restrict__ temp,  // [8]
    float* __restrict__ kvwT,        // [192][384]
    float* __restrict__ pjwT,        // [192][192]
    float* __restrict__ dw32,        // [384][9]
    float* __restrict__ t32)         // [8]
{
    int i = blockIdx.x * 256 + threadIdx.x;
    if (i < 384 * 192) { int co = i / 192, ci = i % 192; kvwT[ci * 384 + co] = kvw[i]; }
    if (i < 192 * 192) { int co = i / 192, ci = i % 192; pjwT[ci * 192 + co] = pjw[i]; }
    if (i < 384 * 9)   dw32[i] = dww[i];
    if (i < 8)         t32[i] = temp[i];
}

// ---------------------------------------------------------------------------
// fold_qw: Wb[t][co][ci] = bf16( sum_cm qdw[co][cm][t] * qw[cm][ci] )
// (k=ci contiguous -> MFMA A-operand loads are 16B-contiguous)
// ---------------------------------------------------------------------------
__global__ __launch_bounds__(192) void fold_qw(
    const float* __restrict__ qw,   // [192 cm][192 ci]
    const float* __restrict__ qdw,  // [192 co][192 cm][9 t]
    uint16_t* __restrict__ Wb)      // [9 t][192 co][192 ci] bf16
{
    int ci = blockIdx.x, t = blockIdx.y;
    int co = threadIdx.x;  // blockDim = 192
    float s = 0.f;
    for (int cm = 0; cm < 192; cm++)
        s = fmaf(qdw[((size_t)co * 192 + cm) * 9 + t], qw[cm * 192 + ci], s);
    Wb[((size_t)t * 192 + co) * 192 + ci] = f2b(s);
}

// ---------------------------------------------------------------------------
// ytrans: y fp32 [b][ci][px] -> Yc bf16 [b][px][ci]  (channel-last)
// LDS tile 64 px x 96 ci-pairs, +1 dword pad -> conflict-free both ways
// ---------------------------------------------------------------------------
__global__ __launch_bounds__(256) void ytrans(
    const float* __restrict__ Y, uint16_t* __restrict__ Yc)
{
    __shared__ uint32_t lt[64 * 97];
    const int b = blockIdx.y;
    const int p0 = blockIdx.x * 64;
    const float* yb = Y + ((size_t)b * 192) * HW + p0;
    for (int i = threadIdx.x; i < 96 * 64; i += 256) {
        int cp = i >> 6, p = i & 63;
        float v0 = yb[(size_t)(2 * cp) * HW + p];
        float v1 = yb[(size_t)(2 * cp + 1) * HW + p];
        lt[p * 97 + cp] = (uint32_t)f2b(v0) | ((uint32_t)f2b(v1) << 16);
    }
    __syncthreads();
    uint32_t* oc = (uint32_t*)(Yc + ((size_t)b * 16384 + p0) * 192);
    for (int i = threadIdx.x; i < 64 * 96; i += 256) {
        int p = i / 96, cp = i - p * 96;
        oc[p * 96 + cp] = lt[p * 97 + cp];
    }
}

// ---------------------------------------------------------------------------
// conv3x3_mfma: Q[co][px] = sum_{ci,t} Wb[t][co][ci] * Yc[px_shift(t)][ci]
// block: 256 thr (4 waves), tile 192co x 128px (spatial 32x4, halo 6x34)
// wave w: co in [w*48, w*48+48) = 3 M-tiles x 8 N-tiles, mfma 16x16x32 bf16
// K-loop: 6 ci-chunks of 32; A-frags from global (L2), B-frags ds_read_b128
// ---------------------------------------------------------------------------
__global__ __launch_bounds__(256) void conv3x3_mfma(
    const uint16_t* __restrict__ Yc, const uint16_t* __restrict__ Wb,
    uint16_t* __restrict__ Q)
{
    __shared__ uint16_t yt[204 * 32];   // [halo px 6*34][ci 32]
    const int b = blockIdx.y;
    const int s = blockIdx.x;           // 128 spatial tiles (4 x-tiles, 32 y-tiles)
    const int tx0 = (s & 3) * 32, ty0 = (s >> 2) * 4;
    const int w = threadIdx.x >> 6, lane = threadIdx.x & 63;
    const int l15 = lane & 15, q4 = lane >> 4;

    f32x4 acc[24];
#pragma unroll
    for (int i = 0; i < 24; i++) acc[i] = (f32x4){0.f, 0.f, 0.f, 0.f};

    const uint16_t* ycb = Yc + (size_t)b * 16384 * 192;

    for (int cc = 0; cc < 6; ++cc) {
        __syncthreads();
        for (int i = threadIdx.x; i < 816; i += 256) {   // 204 px x 4 ci-groups
            int px = i >> 2, cig = i & 3;
            int hy = px / 34, hx = px - hy * 34;
            int gy = ty0 + hy - 1, gx = tx0 + hx - 1;
            u32x4 v = {0u, 0u, 0u, 0u};
            if ((unsigned)gy < 128u && (unsigned)gx < 128u)
                v = *(const u32x4*)(ycb + ((size_t)(gy * 128 + gx)) * 192 + cc * 32 + cig * 8);
            *(u32x4*)(yt + px * 32 + cig * 8) = v;
        }
        __syncthreads();
        for (int t = 0; t < 9; ++t) {
            const int ky = t / 3, kx = t - ky * 3;
            const uint16_t* wbp = Wb + ((size_t)t * 192 + w * 48 + l15) * 192 + cc * 32 + q4 * 8;
            short8 a0 = *(const short8*)(wbp);
            short8 a1 = *(const short8*)(wbp + (size_t)16 * 192);
            short8 a2 = *(const short8*)(wbp + (size_t)32 * 192);
            short8 bf[8];
#pragma unroll
            for (int n = 0; n < 8; ++n) {
                int hp = ((n >> 1) + ky) * 34 + (n & 1) * 16 + kx + l15;
                bf[n] = *(const short8*)(yt + hp * 32 + q4 * 8);
            }
#pragma unroll
            for (int n = 0; n < 8; ++n) {
                acc[n]      = __builtin_amdgcn_mfma_f32_16x16x32_bf16(a0, bf[n], acc[n],      0, 0, 0);
                acc[8 + n]  = __builtin_amdgcn_mfma_f32_16x16x32_bf16(a1, bf[n], acc[8 + n],  0, 0, 0);
                acc[16 + n] = __builtin_amdgcn_mfma_f32_16x16x32_bf16(a2, bf[n], acc[16 + n], 0, 0, 0);
            }
        }
    }
    // epilogue: D layout row(co)=q4*4+r, col(px)=l15
    uint16_t* qb = Q + (size_t)b * 192 * HW;
#pragma unroll
    for (int m = 0; m < 3; ++m)
#pragma unroll
        for (int n = 0; n < 8; ++n) {
            f32x4 v = acc[m * 8 + n];
            int co = w * 48 + m * 16 + q4 * 4;
            int px = (ty0 + (n >> 1)) * WIDTH + tx0 + (n & 1) * 16 + l15;
#pragma unroll
            for (int r = 0; r < 4; ++r)
                qb[(size_t)(co + r) * HW + px] = f2b(v[r]);
        }
}

// ---------------------------------------------------------------------------
// conv1x1: O[b][co][p] = sum_ci WT[ci][co] * X[b][ci][p]
// ---------------------------------------------------------------------------
template <int COUT, typename TIN, typename TOUT>
__global__ __launch_bounds__(256) void conv1x1(
    const TIN* __restrict__ X, const float* __restrict__ WT,
    TOUT* __restrict__ O)
{
    __shared__ uint16_t xt[192 * 128];
    const int b = blockIdx.y;
    const int p0 = blockIdx.x * 128;
    const TIN* xb = X + ((size_t)b * 192) * HW + p0;
    for (int i = threadIdx.x; i < 192 * 128; i += 256)
        xt[i] = f2b(ldv(&xb[((size_t)(i >> 7)) * HW + (i & 127)]));
    __syncthreads();
    const int px  = threadIdx.x & 127;
    const int cog = threadIdx.x >> 7;
    const int coBeg = cog * (COUT / 2);
    TOUT* ob = O + ((size_t)b * COUT) * HW + p0 + px;
    for (int co0 = coBeg; co0 < coBeg + COUT / 2; co0 += 16) {
        float acc[16];
#pragma unroll
        for (int j = 0; j < 16; j++) acc[j] = 0.f;
        for (int ci = 0; ci < 192; ci++) {
            float xv = b2f(xt[(ci << 7) + px]);
            const float* w = WT + ci * COUT + co0;
#pragma unroll
            for (int j = 0; j < 16; j++) acc[j] = fmaf(w[j], xv, acc[j]);
        }
#pragma unroll
        for (int j = 0; j < 16; j++) stv(&ob[((size_t)(co0 + j)) * HW], acc[j]);
    }
}

// ---------------------------------------------------------------------------
// dwconv: depthwise 3x3, SAME zero pad
// ---------------------------------------------------------------------------
__global__ __launch_bounds__(256) void dwconv(
    const uint16_t* __restrict__ KV1, const float* __restrict__ DW,
    uint16_t* __restrict__ KVo)
{
    const int c = blockIdx.y, b = blockIdx.z;
    const int p = blockIdx.x * 256 + threadIdx.x;
    const int yy = p >> 7, xx = p & 127;
    const uint16_t* src = KV1 + ((size_t)b * 384 + c) * HW;
    const float* w = DW + c * 9;
    float acc = 0.f;
#pragma unroll
    for (int ky = 0; ky < 3; ky++) {
        const int ny = yy + ky - 1;
#pragma unroll
        for (int kx = 0; kx < 3; kx++) {
            const int nx = xx + kx - 1;
            float v = ((unsigned)ny < 128u && (unsigned)nx < 128u)
                          ? b2f(src[ny * WIDTH + nx]) : 0.f;
            acc = fmaf(w[ky * 3 + kx], v, acc);
        }
    }
    KVo[((size_t)b * 384 + c) * HW + p] = f2b(acc);
}

// ---------------------------------------------------------------------------
// rownorm: 1/max(||row||,eps) for q rows (which=0) and k rows (which=1)
// ---------------------------------------------------------------------------
__global__ __launch_bounds__(256) void rownorm(
    const uint16_t* __restrict__ Q, const uint16_t* __restrict__ KV,
    float* __restrict__ invq, float* __restrict__ invk)
{
    int idx = blockIdx.x;                 // [b(8)][which(2)][hc(192)]
    int b = idx / 384, rem = idx % 384;
    int which = rem / 192, hc = rem % 192;
    const uint16_t* src = which ? (KV + ((size_t)b * 384 + hc) * HW)
                                : (Q  + ((size_t)b * 192 + hc) * HW);
    float s = 0.f;
    for (int e = threadIdx.x; e < HW; e += 256) {
        float v = b2f(src[e]); s = fmaf(v, v, s);
    }
#pragma unroll
    for (int o = 32; o > 0; o >>= 1) s += __shfl_down(s, o);
    __shared__ float red[4];
    if ((threadIdx.x & 63) == 0) red[threadIdx.x >> 6] = s;
    __syncthreads();
    if (threadIdx.x == 0) {
        float t = red[0] + red[1] + red[2] + red[3];
        (which ? invk : invq)[b * 192 + hc] = 1.f / fmaxf(sqrtf(t), 1e-12f);
    }
}

// ---------------------------------------------------------------------------
// attn_dots: partial (over e-range) raw dot products q_c . k_d
// ---------------------------------------------------------------------------
__global__ __launch_bounds__(256) void attn_dots(
    const uint16_t* __restrict__ Q, const uint16_t* __restrict__ KV,
    float* __restrict__ part)   // [8 s][64 bh][576]
{
    const int s = blockIdx.x, bh = blockIdx.y;
    const int b = bh >> 3, h = bh & 7;
    __shared__ uint16_t qt[24 * 512];
    __shared__ uint16_t kt[24 * 512];
    const uint16_t* qb = Q  + ((size_t)b * 192 + h * 24) * HW;
    const uint16_t* kb = KV + ((size_t)b * 384 + h * 24) * HW;
    float accs[3] = {0.f, 0.f, 0.f};
    for (int st = 0; st < 4; st++) {
        const int e0 = s * 2048 + st * 512;
        __syncthreads();
        for (int i = threadIdx.x; i < 24 * 512; i += 256) {
            int c = i >> 9, e = i & 511;
            qt[i] = qb[(size_t)c * HW + e0 + e];
            kt[i] = kb[(size_t)c * HW + e0 + e];
        }
        __syncthreads();
        int ai = 0;
        for (int pi = threadIdx.x; pi < 576; pi += 256, ai++) {
            int c = pi / 24, d = pi - c * 24;
            const uint16_t* qr = &qt[c << 9];
            const uint16_t* kr = &kt[d << 9];
            float a = 0.f;
            for (int e = 0; e < 512; e++) a = fmaf(b2f(qr[e]), b2f(kr[e]), a);
            accs[ai] += a;
        }
    }
    int ai = 0;
    for (int pi = threadIdx.x; pi < 576; pi += 256, ai++)
        part[((size_t)s * 64 + bh) * 576 + pi] = accs[ai];
}

// ---------------------------------------------------------------------------
// softmax_attn: sum partials, scale by temp*invq*invk, row softmax (24x24)
// ---------------------------------------------------------------------------
__global__ __launch_bounds__(256) void softmax_attn(
    const float* __restrict__ part, const float* __restrict__ t32,
    const float* __restrict__ invq, const float* __restrict__ invk,
    float* __restrict__ prob)   // [64 bh][576]
{
    const int bh = blockIdx.x, b = bh >> 3, h = bh & 7;
    __shared__ float l[576];
    const float t = t32[h];
    for (int pi = threadIdx.x; pi < 576; pi += 256) {
        float ssum = 0.f;
        for (int s = 0; s < 8; s++) ssum += part[((size_t)s * 64 + bh) * 576 + pi];
        int c = pi / 24, d = pi - c * 24;
        l[pi] = t * invq[b * 192 + h * 24 + c] * invk[b * 192 + h * 24 + d] * ssum;
    }
    __syncthreads();
    if (threadIdx.x < 24) {
        const int c = threadIdx.x;
        float m = -1e30f;
#pragma unroll
        for (int d = 0; d < 24; d++) m = fmaxf(m, l[c * 24 + d]);
        float ex[24]; float sum = 0.f;
#pragma unroll
        for (int d = 0; d < 24; d++) { ex[d] = __expf(l[c * 24 + d] - m); sum += ex[d]; }
        const float inv = 1.f / sum;
#pragma unroll
        for (int d = 0; d < 24; d++) prob[(size_t)bh * 576 + c * 24 + d] = ex[d] * inv;
    }
}

// ---------------------------------------------------------------------------
// attn_v: AO[b][h*24+c][e] = sum_d prob[c][d] * v[d][e]
// ---------------------------------------------------------------------------
__global__ __launch_bounds__(256) void attn_v(
    const float* __restrict__ prob, const uint16_t* __restrict__ KV,
    uint16_t* __restrict__ AO)
{
    const int bh = blockIdx.y, b = bh >> 3, h = bh & 7;
    const int e = blockIdx.x * 256 + threadIdx.x;
    __shared__ float a[576];
    for (int i = threadIdx.x; i < 576; i += 256) a[i] = prob[(size_t)bh * 576 + i];
    __syncthreads();
    const uint16_t* vb = KV + ((size_t)b * 384 + 192 + h * 24) * HW + e;
    float acc[24];
#pragma unroll
    for (int c = 0; c < 24; c++) acc[c] = 0.f;
    for (int d = 0; d < 24; d++) {
        float vv = b2f(vb[(size_t)d * HW]);
#pragma unroll
        for (int c = 0; c < 24; c++) acc[c] = fmaf(a[c * 24 + d], vv, acc[c]);
    }
    uint16_t* ob = AO + ((size_t)b * 192 + h * 24) * HW + e;
#pragma unroll
    for (int c = 0; c < 24; c++) ob[(size_t)c * HW] = f2b(acc[c]);
}

// ---------------------------------------------------------------------------
extern "C" void kernel_launch(void* const* d_in, const int* in_sizes, int n_in,
                              void* d_out, int out_size, void* d_ws, size_t ws_size,
                              hipStream_t stream) {
    const float* x    = (const float*)d_in[0];
    const float* y    = (const float*)d_in[1];
    const float* temp = (const float*)d_in[2];
    const float* kvw  = (const float*)d_in[3];
    const float* kvdw = (const float*)d_in[4];
    const float* qw   = (const float*)d_in[5];
    const float* qdw  = (const float*)d_in[6];
    const float* pjw  = (const float*)d_in[7];

    char* ws = (char*)d_ws;
    // region reuse: kv1 [0,100.7MB) dead after dwconv; q and attn-out recycle it
    uint16_t* kv1 = (uint16_t*)(ws + 0);            // 8*384*16384*2 = 100663296
    uint16_t* q   = (uint16_t*)(ws + 0);            // 50331648 (after kv1 dead)
    uint16_t* ao  = (uint16_t*)(ws + 50331648);     // 50331648
    uint16_t* kv  = (uint16_t*)(ws + 100663296);    // 100663296
    uint16_t* Wb  = (uint16_t*)(ws + 201326592);    // 9*192*192*2 = 663552
    float* kvwT   = (float*)(ws + 201990144);       // 294912
    float* pjwT   = (float*)(ws + 202285056);       // 147456
    float* dw32   = (float*)(ws + 202432512);       // 13824
    float* t32    = (float*)(ws + 202446336);       // 32
    float* invq   = (float*)(ws + 202446368);       // 6144
    float* invk   = (float*)(ws + 202452512);       // 6144
    float* part   = (float*)(ws + 202458656);       // 1179648
    float* prob   = (float*)(ws + 203638304);       // 147456 -> 203785760
    uint16_t* Yc  = (uint16_t*)(ws + 203785984);    // 50331648 -> ~254.1 MB total

    prep<<<288, 256, 0, stream>>>(kvw, pjw, kvdw, temp, kvwT, pjwT, dw32, t32);
    fold_qw<<<dim3(192, 9), 192, 0, stream>>>(qw, qdw, Wb);
    ytrans<<<dim3(256, 8), 256, 0, stream>>>(y, Yc);
    conv1x1<384, float, uint16_t><<<dim3(128, 8), 256, 0, stream>>>(x, kvwT, kv1);
    dwconv<<<dim3(64, 384, 8), 256, 0, stream>>>(kv1, dw32, kv);
    conv3x3_mfma<<<dim3(128, 8), 256, 0, stream>>>(Yc, Wb, q);
    rownorm<<<3072, 256, 0, stream>>>(q, kv, invq, invk);
    attn_dots<<<dim3(8, 64), 256, 0, stream>>>(q, kv, part);
    softmax_attn<<<64, 256, 0, stream>>>(part, t32, invq, invk, prob);
    attn_v<<<dim3(64, 64), 256, 0, stream>>>(prob, kv, ao);
    conv1x1<192, uint16_t, float><<<dim3(128, 8), 256, 0, stream>>>(ao, pjwT, (float*)d_out);
}

// Round 4
// 1143.522 us; speedup vs baseline: 6.8034x; 2.1838x over previous
//
#include <hip/hip_runtime.h>
#include <stdint.h>

// Problem: B=8, C=192, HEADS=8, hd=24, H=W=128, hw=16384.
// I/O tensors fp32 (per reference); big intermediates bf16; fp32 accumulation.
// conv3x3 (q path) and both 1x1 convs = MFMA implicit GEMM (16x16x32 bf16).

#define HW 16384
#define WIDTH 128

typedef __attribute__((ext_vector_type(8))) short short8;   // 8 bf16 = 4 VGPRs
typedef __attribute__((ext_vector_type(4))) float f32x4;
typedef __attribute__((ext_vector_type(4))) unsigned int u32x4;

__device__ __forceinline__ float b2f(uint16_t u) {
    union { uint32_t i; float f; } v; v.i = (uint32_t)u << 16; return v.f;
}
__device__ __forceinline__ uint16_t f2b(float f) {
    union { float f; uint32_t i; } v; v.f = f;
    uint32_t r = v.i + 0x7FFFu + ((v.i >> 16) & 1u);
    return (uint16_t)(r >> 16);
}
__device__ __forceinline__ float ldv(const float* p) { return *p; }
__device__ __forceinline__ float ldv(const uint16_t* p) { return b2f(*p); }
__device__ __forceinline__ void stv(float* p, float v) { *p = v; }
__device__ __forceinline__ void stv(uint16_t* p, float v) { *p = f2b(v); }

// ---------------------------------------------------------------------------
// prep: cast 1x1 weights to bf16 [co][ci] (A-operand, k-contiguous);
//       copy dw weights + temperature to fp32
// ---------------------------------------------------------------------------
__global__ __launch_bounds__(256) void prep(
    const float* __restrict__ kvw,   // [384][192]
    const float* __restrict__ pjw,   // [192][192]
    const float* __restrict__ dww,   // [384][9]
    const float* __restrict__ temp,  // [8]
    uint16_t* __restrict__ Wkvb,     // [384][192] bf16
    uint16_t* __restrict__ Wpjb,     // [192][192] bf16
    float* __restrict__ dw32,        // [384][9]
    float* __restrict__ t32)         // [8]
{
    int i = blockIdx.x * 256 + threadIdx.x;
    if (i < 384 * 192) Wkvb[i] = f2b(kvw[i]);
    if (i < 192 * 192) Wpjb[i] = f2b(pjw[i]);
    if (i < 384 * 9)   dw32[i] = dww[i];
    if (i < 8)         t32[i] = temp[i];
}

// ---------------------------------------------------------------------------
// fold_qw: Wb[t][co][ci] = bf16( sum_cm qdw[co][cm][t] * qw[cm][ci] )
// ---------------------------------------------------------------------------
__global__ __launch_bounds__(192) void fold_qw(
    const float* __restrict__ qw,   // [192 cm][192 ci]
    const float* __restrict__ qdw,  // [192 co][192 cm][9 t]
    uint16_t* __restrict__ Wb)      // [9 t][192 co][192 ci] bf16
{
    int ci = blockIdx.x, t = blockIdx.y;
    int co = threadIdx.x;  // blockDim = 192
    float s = 0.f;
    for (int cm = 0; cm < 192; cm++)
        s = fmaf(qdw[((size_t)co * 192 + cm) * 9 + t], qw[cm * 192 + ci], s);
    Wb[((size_t)t * 192 + co) * 192 + ci] = f2b(s);
}

// ---------------------------------------------------------------------------
// ctrans: fp32 [b][ci][px] -> bf16 channel-last [b][px][ci]
// LDS tile 64 px x 96 ci-pairs, +1 dword pad -> conflict-free both ways
// ---------------------------------------------------------------------------
__global__ __launch_bounds__(256) void ctrans(
    const float* __restrict__ Y, uint16_t* __restrict__ Yc)
{
    __shared__ uint32_t lt[64 * 97];
    const int b = blockIdx.y;
    const int p0 = blockIdx.x * 64;
    const float* yb = Y + ((size_t)b * 192) * HW + p0;
    for (int i = threadIdx.x; i < 96 * 64; i += 256) {
        int cp = i >> 6, p = i & 63;
        float v0 = yb[(size_t)(2 * cp) * HW + p];
        float v1 = yb[(size_t)(2 * cp + 1) * HW + p];
        lt[p * 97 + cp] = (uint32_t)f2b(v0) | ((uint32_t)f2b(v1) << 16);
    }
    __syncthreads();
    uint32_t* oc = (uint32_t*)(Yc + ((size_t)b * 16384 + p0) * 192);
    for (int i = threadIdx.x; i < 64 * 96; i += 256) {
        int p = i / 96, cp = i - p * 96;
        oc[p * 96 + cp] = lt[p * 97 + cp];
    }
}

// ---------------------------------------------------------------------------
// conv1x1_mfma: O[b][co][px] = sum_ci W[co][ci] * Xc[b][px][ci]
// barrier-free: A-frags (weights, L2-resident) and B-frags (contiguous
// 64px x 192ci slice, read exactly once) straight from global.
// block = 4 waves; wave w: co in [w*COUT/4, ...) = COUT/64 M-tiles x 4 N-tiles
// ---------------------------------------------------------------------------
template <int COUT, typename TOUT>
__global__ __launch_bounds__(256) void conv1x1_mfma(
    const uint16_t* __restrict__ Wbf,  // [COUT][192] bf16
    const uint16_t* __restrict__ Xc,   // [b][16384][192] bf16
    TOUT* __restrict__ O)              // [b][COUT][16384]
{
    constexpr int MT = COUT / 64;      // M-tiles per wave
    const int b = blockIdx.y;
    const int p0 = blockIdx.x * 64;
    const int w = threadIdx.x >> 6, lane = threadIdx.x & 63;
    const int l15 = lane & 15, q4 = lane >> 4;
    const int cob = w * (COUT / 4);

    f32x4 acc[MT * 4];
#pragma unroll
    for (int i = 0; i < MT * 4; i++) acc[i] = (f32x4){0.f, 0.f, 0.f, 0.f};

    const uint16_t* xb = Xc + ((size_t)b * 16384 + p0) * 192;

#pragma unroll
    for (int cc = 0; cc < 6; ++cc) {
        short8 a[MT], bf[4];
#pragma unroll
        for (int m = 0; m < MT; ++m)
            a[m] = *(const short8*)(Wbf + ((size_t)(cob + m * 16 + l15)) * 192 + cc * 32 + q4 * 8);
#pragma unroll
        for (int n = 0; n < 4; ++n)
            bf[n] = *(const short8*)(xb + ((size_t)(n * 16 + l15)) * 192 + cc * 32 + q4 * 8);
#pragma unroll
        for (int m = 0; m < MT; ++m)
#pragma unroll
            for (int n = 0; n < 4; ++n)
                acc[m * 4 + n] = __builtin_amdgcn_mfma_f32_16x16x32_bf16(a[m], bf[n], acc[m * 4 + n], 0, 0, 0);
    }
    TOUT* ob = O + (size_t)b * COUT * HW;
#pragma unroll
    for (int m = 0; m < MT; ++m)
#pragma unroll
        for (int n = 0; n < 4; ++n) {
            f32x4 v = acc[m * 4 + n];
            int co = cob + m * 16 + q4 * 4;
            int px = p0 + n * 16 + l15;
#pragma unroll
            for (int r = 0; r < 4; ++r)
                stv(&ob[(size_t)(co + r) * HW + px], v[r]);
        }
}

// ---------------------------------------------------------------------------
// conv3x3_mfma: Q[co][px] = sum_{ci,t} Wb[t][co][ci] * Yc[px_shift(t)][ci]
// ---------------------------------------------------------------------------
__global__ __launch_bounds__(256) void conv3x3_mfma(
    const uint16_t* __restrict__ Yc, const uint16_t* __restrict__ Wb,
    uint16_t* __restrict__ Q)
{
    __shared__ uint16_t yt[204 * 32];   // [halo px 6*34][ci 32]
    const int b = blockIdx.y;
    const int s = blockIdx.x;           // 128 spatial tiles (4 x-tiles, 32 y-tiles)
    const int tx0 = (s & 3) * 32, ty0 = (s >> 2) * 4;
    const int w = threadIdx.x >> 6, lane = threadIdx.x & 63;
    const int l15 = lane & 15, q4 = lane >> 4;

    f32x4 acc[24];
#pragma unroll
    for (int i = 0; i < 24; i++) acc[i] = (f32x4){0.f, 0.f, 0.f, 0.f};

    const uint16_t* ycb = Yc + (size_t)b * 16384 * 192;

    for (int cc = 0; cc < 6; ++cc) {
        __syncthreads();
        for (int i = threadIdx.x; i < 816; i += 256) {   // 204 px x 4 ci-groups
            int px = i >> 2, cig = i & 3;
            int hy = px / 34, hx = px - hy * 34;
            int gy = ty0 + hy - 1, gx = tx0 + hx - 1;
            u32x4 v = {0u, 0u, 0u, 0u};
            if ((unsigned)gy < 128u && (unsigned)gx < 128u)
                v = *(const u32x4*)(ycb + ((size_t)(gy * 128 + gx)) * 192 + cc * 32 + cig * 8);
            *(u32x4*)(yt + px * 32 + cig * 8) = v;
        }
        __syncthreads();
        for (int t = 0; t < 9; ++t) {
            const int ky = t / 3, kx = t - ky * 3;
            const uint16_t* wbp = Wb + ((size_t)t * 192 + w * 48 + l15) * 192 + cc * 32 + q4 * 8;
            short8 a0 = *(const short8*)(wbp);
            short8 a1 = *(const short8*)(wbp + (size_t)16 * 192);
            short8 a2 = *(const short8*)(wbp + (size_t)32 * 192);
            short8 bf[8];
#pragma unroll
            for (int n = 0; n < 8; ++n) {
                int hp = ((n >> 1) + ky) * 34 + (n & 1) * 16 + kx + l15;
                bf[n] = *(const short8*)(yt + hp * 32 + q4 * 8);
            }
#pragma unroll
            for (int n = 0; n < 8; ++n) {
                acc[n]      = __builtin_amdgcn_mfma_f32_16x16x32_bf16(a0, bf[n], acc[n],      0, 0, 0);
                acc[8 + n]  = __builtin_amdgcn_mfma_f32_16x16x32_bf16(a1, bf[n], acc[8 + n],  0, 0, 0);
                acc[16 + n] = __builtin_amdgcn_mfma_f32_16x16x32_bf16(a2, bf[n], acc[16 + n], 0, 0, 0);
            }
        }
    }
    uint16_t* qb = Q + (size_t)b * 192 * HW;
#pragma unroll
    for (int m = 0; m < 3; ++m)
#pragma unroll
        for (int n = 0; n < 8; ++n) {
            f32x4 v = acc[m * 8 + n];
            int co = w * 48 + m * 16 + q4 * 4;
            int px = (ty0 + (n >> 1)) * WIDTH + tx0 + (n & 1) * 16 + l15;
#pragma unroll
            for (int r = 0; r < 4; ++r)
                qb[(size_t)(co + r) * HW + px] = f2b(v[r]);
        }
}

// ---------------------------------------------------------------------------
// dwconv: depthwise 3x3, SAME zero pad
// ---------------------------------------------------------------------------
__global__ __launch_bounds__(256) void dwconv(
    const uint16_t* __restrict__ KV1, const float* __restrict__ DW,
    uint16_t* __restrict__ KVo)
{
    const int c = blockIdx.y, b = blockIdx.z;
    const int p = blockIdx.x * 256 + threadIdx.x;
    const int yy = p >> 7, xx = p & 127;
    const uint16_t* src = KV1 + ((size_t)b * 384 + c) * HW;
    const float* w = DW + c * 9;
    float acc = 0.f;
#pragma unroll
    for (int ky = 0; ky < 3; ky++) {
        const int ny = yy + ky - 1;
#pragma unroll
        for (int kx = 0; kx < 3; kx++) {
            const int nx = xx + kx - 1;
            float v = ((unsigned)ny < 128u && (unsigned)nx < 128u)
                          ? b2f(src[ny * WIDTH + nx]) : 0.f;
            acc = fmaf(w[ky * 3 + kx], v, acc);
        }
    }
    KVo[((size_t)b * 384 + c) * HW + p] = f2b(acc);
}

// ---------------------------------------------------------------------------
// rownorm: 1/max(||row||,eps) for q rows (which=0) and k rows (which=1)
// ---------------------------------------------------------------------------
__global__ __launch_bounds__(256) void rownorm(
    const uint16_t* __restrict__ Q, const uint16_t* __restrict__ KV,
    float* __restrict__ invq, float* __restrict__ invk)
{
    int idx = blockIdx.x;                 // [b(8)][which(2)][hc(192)]
    int b = idx / 384, rem = idx % 384;
    int which = rem / 192, hc = rem % 192;
    const uint16_t* src = which ? (KV + ((size_t)b * 384 + hc) * HW)
                                : (Q  + ((size_t)b * 192 + hc) * HW);
    float s = 0.f;
    for (int e = threadIdx.x; e < HW; e += 256) {
        float v = b2f(src[e]); s = fmaf(v, v, s);
    }
#pragma unroll
    for (int o = 32; o > 0; o >>= 1) s += __shfl_down(s, o);
    __shared__ float red[4];
    if ((threadIdx.x & 63) == 0) red[threadIdx.x >> 6] = s;
    __syncthreads();
    if (threadIdx.x == 0) {
        float t = red[0] + red[1] + red[2] + red[3];
        (which ? invk : invq)[b * 192 + hc] = 1.f / fmaxf(sqrtf(t), 1e-12f);
    }
}

// ---------------------------------------------------------------------------
// attn_dots: partial (over e-range) raw dot products q_c . k_d
// ---------------------------------------------------------------------------
__global__ __launch_bounds__(256) void attn_dots(
    const uint16_t* __restrict__ Q, const uint16_t* __restrict__ KV,
    float* __restrict__ part)   // [8 s][64 bh][576]
{
    const int s = blockIdx.x, bh = blockIdx.y;
    const int b = bh >> 3, h = bh & 7;
    __shared__ uint16_t qt[24 * 512];
    __shared__ uint16_t kt[24 * 512];
    const uint16_t* qb = Q  + ((size_t)b * 192 + h * 24) * HW;
    const uint16_t* kb = KV + ((size_t)b * 384 + h * 24) * HW;
    float accs[3] = {0.f, 0.f, 0.f};
    for (int st = 0; st < 4; st++) {
        const int e0 = s * 2048 + st * 512;
        __syncthreads();
        for (int i = threadIdx.x; i < 24 * 512; i += 256) {
            int c = i >> 9, e = i & 511;
            qt[i] = qb[(size_t)c * HW + e0 + e];
            kt[i] = kb[(size_t)c * HW + e0 + e];
        }
        __syncthreads();
        int ai = 0;
        for (int pi = threadIdx.x; pi < 576; pi += 256, ai++) {
            int c = pi / 24, d = pi - c * 24;
            const uint16_t* qr = &qt[c << 9];
            const uint16_t* kr = &kt[d << 9];
            float a = 0.f;
            for (int e = 0; e < 512; e++) a = fmaf(b2f(qr[e]), b2f(kr[e]), a);
            accs[ai] += a;
        }
    }
    int ai = 0;
    for (int pi = threadIdx.x; pi < 576; pi += 256, ai++)
        part[((size_t)s * 64 + bh) * 576 + pi] = accs[ai];
}

// ---------------------------------------------------------------------------
// softmax_attn: sum partials, scale by temp*invq*invk, row softmax (24x24)
// ---------------------------------------------------------------------------
__global__ __launch_bounds__(256) void softmax_attn(
    const float* __restrict__ part, const float* __restrict__ t32,
    const float* __restrict__ invq, const float* __restrict__ invk,
    float* __restrict__ prob)   // [64 bh][576]
{
    const int bh = blockIdx.x, b = bh >> 3, h = bh & 7;
    __shared__ float l[576];
    const float t = t32[h];
    for (int pi = threadIdx.x; pi < 576; pi += 256) {
        float ssum = 0.f;
        for (int s = 0; s < 8; s++) ssum += part[((size_t)s * 64 + bh) * 576 + pi];
        int c = pi / 24, d = pi - c * 24;
        l[pi] = t * invq[b * 192 + h * 24 + c] * invk[b * 192 + h * 24 + d] * ssum;
    }
    __syncthreads();
    if (threadIdx.x < 24) {
        const int c = threadIdx.x;
        float m = -1e30f;
#pragma unroll
        for (int d = 0; d < 24; d++) m = fmaxf(m, l[c * 24 + d]);
        float ex[24]; float sum = 0.f;
#pragma unroll
        for (int d = 0; d < 24; d++) { ex[d] = __expf(l[c * 24 + d] - m); sum += ex[d]; }
        const float inv = 1.f / sum;
#pragma unroll
        for (int d = 0; d < 24; d++) prob[(size_t)bh * 576 + c * 24 + d] = ex[d] * inv;
    }
}

// ---------------------------------------------------------------------------
// attn_v: AOc[b][e][h*24+c] = sum_d prob[c][d] * v[d][e]   (channel-last out)
// ---------------------------------------------------------------------------
__global__ __launch_bounds__(256) void attn_v(
    const float* __restrict__ prob, const uint16_t* __restrict__ KV,
    uint16_t* __restrict__ AOc)
{
    const int bh = blockIdx.y, b = bh >> 3, h = bh & 7;
    const int e = blockIdx.x * 256 + threadIdx.x;
    __shared__ float a[576];
    for (int i = threadIdx.x; i < 576; i += 256) a[i] = prob[(size_t)bh * 576 + i];
    __syncthreads();
    const uint16_t* vb = KV + ((size_t)b * 384 + 192 + h * 24) * HW + e;
    float acc[24];
#pragma unroll
    for (int c = 0; c < 24; c++) acc[c] = 0.f;
    for (int d = 0; d < 24; d++) {
        float vv = b2f(vb[(size_t)d * HW]);
#pragma unroll
        for (int c = 0; c < 24; c++) acc[c] = fmaf(a[c * 24 + d], vv, acc[c]);
    }
    uint32_t packed[12];
#pragma unroll
    for (int j = 0; j < 12; j++)
        packed[j] = (uint32_t)f2b(acc[2 * j]) | ((uint32_t)f2b(acc[2 * j + 1]) << 16);
    uint32_t* ob = (uint32_t*)(AOc + ((size_t)b * 16384 + e) * 192 + h * 24);
#pragma unroll
    for (int j = 0; j < 3; j++)
        *(u32x4*)(ob + 4 * j) = *(u32x4*)(packed + 4 * j);
}

// ---------------------------------------------------------------------------
extern "C" void kernel_launch(void* const* d_in, const int* in_sizes, int n_in,
                              void* d_out, int out_size, void* d_ws, size_t ws_size,
                              hipStream_t stream) {
    const float* x    = (const float*)d_in[0];
    const float* y    = (const float*)d_in[1];
    const float* temp = (const float*)d_in[2];
    const float* kvw  = (const float*)d_in[3];
    const float* kvdw = (const float*)d_in[4];
    const float* qw   = (const float*)d_in[5];
    const float* qdw  = (const float*)d_in[6];
    const float* pjw  = (const float*)d_in[7];

    char* ws = (char*)d_ws;
    // region reuse: kv1 [0,100.7MB) dead after dwconv; q and AOc recycle it.
    // Tc (channel-last transpose buf) serves x first (kv GEMM), then y (conv3x3).
    uint16_t* kv1 = (uint16_t*)(ws + 0);            // 8*384*16384*2 = 100663296
    uint16_t* q   = (uint16_t*)(ws + 0);            // 50331648 (after kv1 dead)
    uint16_t* AOc = (uint16_t*)(ws + 50331648);     // 50331648
    uint16_t* kv  = (uint16_t*)(ws + 100663296);    // 100663296
    uint16_t* Wb  = (uint16_t*)(ws + 201326592);    // 9*192*192*2 = 663552
    uint16_t* Wkvb= (uint16_t*)(ws + 201990144);    // 147456
    uint16_t* Wpjb= (uint16_t*)(ws + 202137600);    // 73728
    float* dw32   = (float*)(ws + 202211328);       // 13824
    float* t32    = (float*)(ws + 202225152);       // 32
    float* invq   = (float*)(ws + 202225184);       // 6144
    float* invk   = (float*)(ws + 202231328);       // 6144
    float* part   = (float*)(ws + 202237472);       // 1179648
    float* prob   = (float*)(ws + 203417120);       // 147456 -> 203564576
    uint16_t* Tc  = (uint16_t*)(ws + 203564576);    // 50331648 -> ~253.9 MB total

    prep<<<288, 256, 0, stream>>>(kvw, pjw, kvdw, temp, Wkvb, Wpjb, dw32, t32);
    fold_qw<<<dim3(192, 9), 192, 0, stream>>>(qw, qdw, Wb);
    ctrans<<<dim3(256, 8), 256, 0, stream>>>(x, Tc);
    conv1x1_mfma<384, uint16_t><<<dim3(256, 8), 256, 0, stream>>>(Wkvb, Tc, kv1);
    dwconv<<<dim3(64, 384, 8), 256, 0, stream>>>(kv1, dw32, kv);
    ctrans<<<dim3(256, 8), 256, 0, stream>>>(y, Tc);
    conv3x3_mfma<<<dim3(128, 8), 256, 0, stream>>>(Tc, Wb, q);
    rownorm<<<3072, 256, 0, stream>>>(q, kv, invq, invk);
    attn_dots<<<dim3(8, 64), 256, 0, stream>>>(q, kv, part);
    softmax_attn<<<64, 256, 0, stream>>>(part, t32, invq, invk, prob);
    attn_v<<<dim3(64, 64), 256, 0, stream>>>(prob, kv, AOc);
    conv1x1_mfma<192, float><<<dim3(256, 8), 256, 0, stream>>>(Wpjb, AOc, (float*)d_out);
}